// Round 1
// baseline (808.046 us; speedup 1.0000x reference)
//
#include <hip/hip_runtime.h>
#include <math.h>

// Problem constants (from setup_inputs): inputs (T,B,L) f32, trans (L,L) f32,
// targets (B,S) i32, input_lengths (B,) i32, target_lengths (B,) i32.
constexpr int T_ = 2048, B_ = 64, L_ = 64, S_ = 256;
constexpr float NEGV = -1e30f;

__device__ __forceinline__ float wave_max64(float v) {
#pragma unroll
  for (int off = 1; off < 64; off <<= 1) v = fmaxf(v, __shfl_xor(v, off, 64));
  return v;
}
__device__ __forceinline__ float wave_sum64(float v) {
#pragma unroll
  for (int off = 1; off < 64; off <<= 1) v += __shfl_xor(v, off, 64);
  return v;
}

// One block per batch element b. 128 threads = 2 waves.
//   wave 0: fcc scan (64 states, lane = state j)
//   wave 1: fac scan (256 states, 4 contiguous states per lane)
// Input rows (t,b,:) are staged through LDS in 32-row chunks, double-pumped
// through registers (load chunk c+2 to regs while consuming chunk c from LDS).
__global__ __launch_bounds__(128) void asg_fused(
    const float* __restrict__ inputs, const float* __restrict__ trans,
    const int* __restrict__ targets, const int* __restrict__ ilen,
    const int* __restrict__ tlenp, float* __restrict__ ws) {
  const int b = blockIdx.x;
  const int tid = threadIdx.x;
  const int lane = tid & 63;
  const int wv = tid >> 6;

  __shared__ __align__(16) float stage[32 * 64];  // 8 KB: rows t%32
  __shared__ __align__(16) float Ebuf[64];        // fcc: exp(alpha - M)

  const int len = ilen[b];            // uniform per block
  const int nc = (len + 31) >> 5;     // chunks covering t in [0, len)

  // --- register staging: each thread owns 4 float4 (16 floats) of a chunk ---
  float4 rb0, rb1, rb2, rb3;
  auto load_chunk = [&](int t0) {
#pragma unroll
    for (int i = 0; i < 4; ++i) {
      int f = i * 128 + tid;                  // float4 index within chunk
      int r = t0 + (f >> 4);                  // row (16 float4 per 64-f row)
      r = min(r, T_ - 1);                     // clamp overrun rows (harmless)
      const float4 v = *reinterpret_cast<const float4*>(
          inputs + (size_t)r * (B_ * L_) + b * L_ + (f & 15) * 4);
      if (i == 0) rb0 = v; else if (i == 1) rb1 = v;
      else if (i == 2) rb2 = v; else rb3 = v;
    }
  };
  auto store_chunk = [&]() {
    float4* s4 = reinterpret_cast<float4*>(stage);
    s4[0 * 128 + tid] = rb0;
    s4[1 * 128 + tid] = rb1;
    s4[2 * 128 + tid] = rb2;
    s4[3 * 128 + tid] = rb3;
  };

  // prologue: chunk0 -> LDS, start chunk1 -> regs
  load_chunk(0);
  store_chunk();
  __syncthreads();
  load_chunk(32);

  if (wv == 0) {
    // ===================== FCC =====================
    // W[j,k] = exp(trans[j,k]) constant; s_j = sum_k W[j,k] * exp(alpha_k - M)
    float W[64];
#pragma unroll
    for (int k4 = 0; k4 < 16; ++k4) {
      float4 t4 = *reinterpret_cast<const float4*>(trans + lane * 64 + k4 * 4);
      W[k4 * 4 + 0] = __expf(t4.x);
      W[k4 * 4 + 1] = __expf(t4.y);
      W[k4 * 4 + 2] = __expf(t4.z);
      W[k4 * 4 + 3] = __expf(t4.w);
    }
    float a0 = stage[lane];  // alpha_0 = inputs[0,b,j]
    float M = wave_max64(a0);
    Ebuf[lane] = __expf(a0 - M);

    for (int c = 0; c < nc; ++c) {
      const int tb = max(1, c * 32), te = min(len, c * 32 + 32);
      for (int t = tb; t < te; ++t) {
        const float* row = stage + ((t & 31) << 6);
        float x = row[lane];
        float s0 = 0.f, s1 = 0.f, s2 = 0.f, s3 = 0.f;
#pragma unroll
        for (int k = 0; k < 64; k += 4) {
          float4 e = *reinterpret_cast<const float4*>(Ebuf + k);  // broadcast
          s0 = fmaf(W[k + 0], e.x, s0);
          s1 = fmaf(W[k + 1], e.y, s1);
          s2 = fmaf(W[k + 2], e.z, s2);
          s3 = fmaf(W[k + 3], e.w, s3);
        }
        float s = (s0 + s1) + (s2 + s3);
        float anew = x + M + __logf(s);
        // exact max resync every 4 steps; any uniform M is mathematically
        // exact, drift <= ~10/step keeps exp() in fp32 range.
        if ((t & 3) == 0) M = wave_max64(anew);
        Ebuf[lane] = __expf(anew - M);  // single wave: lockstep, no barrier
      }
      if (c + 1 < nc) {
        __syncthreads();   // everyone done reading chunk c
        store_chunk();     // chunk c+1: regs -> LDS (vmcnt via reg dep)
        load_chunk((c + 2) * 32);  // prefetch chunk c+2 -> regs
        __syncthreads();   // chunk c+1 visible
      }
    }
    float ssum = wave_sum64(Ebuf[lane]);
    if (lane == 0) ws[b] = M + __logf(ssum);  // full[b]
  } else {
    // ===================== FAC =====================
    const int tl = tlenp[b];
    int4 t4 = *reinterpret_cast<const int4*>(targets + b * S_ + lane * 4);
    const int tg0 = t4.x, tg1 = t4.y, tg2 = t4.z, tg3 = t4.w;
    const int tgm1 = (lane > 0) ? targets[b * S_ + lane * 4 - 1] : 0;
    const float st0 = trans[tg0 * 64 + tg0], st1 = trans[tg1 * 64 + tg1];
    const float st2 = trans[tg2 * 64 + tg2], st3 = trans[tg3 * 64 + tg3];
    const float mt0 = (lane == 0) ? NEGV : trans[tg0 * 64 + tgm1];
    const float mt1 = trans[tg1 * 64 + tg0];
    const float mt2 = trans[tg2 * 64 + tg1];
    const float mt3 = trans[tg3 * 64 + tg2];
    float a0 = (lane == 0) ? stage[tg0] : NEGV;  // alpha0[:,0]=emit[0,b,0]
    float a1 = NEGV, a2 = NEGV, a3 = NEGV;

    for (int c = 0; c < nc; ++c) {
      const int tb = max(1, c * 32), te = min(len, c * 32 + 32);
      for (int t = tb; t < te; ++t) {
        const float* row = stage + ((t & 31) << 6);
        float e0 = row[tg0], e1 = row[tg1], e2 = row[tg2], e3 = row[tg3];
        float sh0 = __shfl_up(a3, 1, 64);  // alpha[s-1] across lane boundary
        if (lane == 0) sh0 = NEGV;
        float u, v, mx, mn;
        u = a0 + st0; v = sh0 + mt0; mx = fmaxf(u, v); mn = fminf(u, v);
        float n0 = e0 + mx + __logf(1.0f + __expf(mn - mx));
        u = a1 + st1; v = a0 + mt1; mx = fmaxf(u, v); mn = fminf(u, v);
        float n1 = e1 + mx + __logf(1.0f + __expf(mn - mx));
        u = a2 + st2; v = a1 + mt2; mx = fmaxf(u, v); mn = fminf(u, v);
        float n2 = e2 + mx + __logf(1.0f + __expf(mn - mx));
        u = a3 + st3; v = a2 + mt3; mx = fmaxf(u, v); mn = fminf(u, v);
        float n3 = e3 + mx + __logf(1.0f + __expf(mn - mx));
        a0 = n0; a1 = n1; a2 = n2; a3 = n3;
      }
      if (c + 1 < nc) {
        __syncthreads();
        store_chunk();
        load_chunk((c + 2) * 32);
        __syncthreads();
      }
    }
    const int idx = tl - 1;
    if ((idx >> 2) == lane) {  // static-index extraction (avoid scratch)
      const int r3 = idx & 3;
      float res = (r3 == 0) ? a0 : (r3 == 1) ? a1 : (r3 == 2) ? a2 : a3;
      ws[B_ + b] = res;  // aligned[b]
    }
  }
}

__global__ void asg_combine(const float* __restrict__ ws,
                            float* __restrict__ out) {
  const int j = threadIdx.x;  // 64 threads
  float d = ws[j] - ws[B_ + j];
  d = wave_sum64(d);
  if (j == 0) out[0] = d * (1.0f / 64.0f);
}

extern "C" void kernel_launch(void* const* d_in, const int* in_sizes, int n_in,
                              void* d_out, int out_size, void* d_ws,
                              size_t ws_size, hipStream_t stream) {
  const float* inputs = (const float*)d_in[0];
  const float* trans = (const float*)d_in[1];
  const int* targets = (const int*)d_in[2];
  const int* ilen = (const int*)d_in[3];
  const int* tlen = (const int*)d_in[4];
  float* ws = (float*)d_ws;
  float* out = (float*)d_out;

  hipLaunchKernelGGL(asg_fused, dim3(B_), dim3(128), 0, stream,
                     inputs, trans, targets, ilen, tlen, ws);
  hipLaunchKernelGGL(asg_combine, dim3(1), dim3(64), 0, stream, ws, out);
}